// Round 20
// baseline (123.946 us; speedup 1.0000x reference)
//
#include <hip/hip_runtime.h>
#include <hip/hip_bf16.h>

typedef __bf16 bf16_t;
typedef __bf16 bf16x8 __attribute__((ext_vector_type(8)));
typedef float f32x4 __attribute__((ext_vector_type(4)));
typedef float f32x16 __attribute__((ext_vector_type(16)));
typedef unsigned short u16;

#define DEVI __device__ __forceinline__
#define MFMA16x16x32(A, B, C) __builtin_amdgcn_mfma_f32_16x16x32_bf16(A, B, C, 0, 0, 0)
#define MFMA32x32x16(A, B, C) __builtin_amdgcn_mfma_f32_32x32x16_bf16(A, B, C, 0, 0, 0)

DEVI void gload_lds16(const void* g, void* l) {
  __builtin_amdgcn_global_load_lds(
      (const __attribute__((address_space(1))) void*)g,
      (__attribute__((address_space(3))) void*)l, 16, 0, 0);
}

DEVI u16 bits_of(bf16_t x) { return __builtin_bit_cast(u16, x); }

DEVI unsigned pk2(float lo, float hi) {
  return (unsigned)bits_of((bf16_t)lo) | ((unsigned)bits_of((bf16_t)hi) << 16);
}

DEVI bf16x8 mk_frag(unsigned s0, unsigned s1, unsigned s2, unsigned s3) {
  int4 t;
  t.x = (int)s0; t.y = (int)s1; t.z = (int)s2; t.w = (int)s3;
  return __builtin_bit_cast(bf16x8, t);
}

#if __has_builtin(__builtin_amdgcn_exp2f)
DEVI float exp2_fast(float x) { return __builtin_amdgcn_exp2f(x); }
#else
DEVI float exp2_fast(float x) { return __exp2f(x); }
#endif

// ---------------- fused fp32 -> bf16 conversion: X + 4 weight matrices ----------------
__global__ void cvt_all(const float4* __restrict__ X,
                        const float4* __restrict__ Wq, const float4* __restrict__ Wk,
                        const float4* __restrict__ Wv, const float4* __restrict__ Wo,
                        ushort4* __restrict__ out) {
  int i = blockIdx.x * 256 + threadIdx.x;   // 0 .. 2097151 float4s
  const float4* src;
  int off;
  if (i < 1048576) { src = X; off = i; }
  else {
    int j = i - 1048576;
    int seg = j >> 18;
    off = j & 262143;
    src = (seg == 0) ? Wq : (seg == 1) ? Wk : (seg == 2) ? Wv : Wo;
  }
  float4 v = src[off];
  ushort4 o;
  o.x = bits_of((bf16_t)v.x);
  o.y = bits_of((bf16_t)v.y);
  o.z = bits_of((bf16_t)v.z);
  o.w = bits_of((bf16_t)v.w);
  out[i] = o;
}

// ---------------- QKV GEMM: 128x128 tile, BK=64, bf16 out ----------------
// R20: BK 32->64 halves the per-K-tile barrier count (the m97-structure ~20% drain).
// Same register footprint: inner loop makes 2 k-passes over af[4]/bfr[4]. LDS 32 KB
// (3 blocks/CU retained). 128B LDS rows require the G4 swizzle: gload_lds source slot
// (l&7)^(l>>3) + read-side ^((row&7)<<4) -- pattern cloned from attn K staging (R5-proven).
__global__ __launch_bounds__(256, 3) void gemm_bt(
    const bf16_t* __restrict__ A,
    const bf16_t* __restrict__ W0, const bf16_t* __restrict__ W1, const bf16_t* __restrict__ W2,
    const float* __restrict__ b0, const float* __restrict__ b1, const float* __restrict__ b2,
    bf16_t* o0, bf16_t* o1, bf16_t* o2, float s0, float s1, float s2) {
  constexpr int K = 1024, N = 1024;
  const int z = blockIdx.z;
  const bf16_t* W = (z == 0) ? W0 : ((z == 1) ? W1 : W2);
  const float* bias = (z == 0) ? b0 : ((z == 1) ? b1 : b2);
  bf16_t* out = (z == 0) ? o0 : ((z == 1) ? o1 : o2);
  const float scale = (z == 0) ? s0 : ((z == 1) ? s1 : s2);

  __shared__ bf16_t As[128 * 64];   // [row][k] 128B rows, swizzled
  __shared__ bf16_t Bs[128 * 64];

  const int tid = threadIdx.x;
  const int wave = tid >> 6, lane = tid & 63;
  const int g = lane >> 4, l15 = lane & 15;
  const long m0 = (long)blockIdx.x * 128;
  const long n0 = (long)blockIdx.y * 128;

  // staging: 16 chunks of 1 KB (8 rows x 128B) per matrix; 4 per wave; swizzled source
  const int srow8 = lane >> 3;                 // row within 8-row chunk
  const int sslot = (lane & 7) ^ srow8;        // 16B source slot (XOR swizzle)

  const int wr = (wave >> 1) * 64;
  const int wc = (wave & 1) * 64;

  f32x4 acc[4][4] = {};

  for (int k0 = 0; k0 < K; k0 += 64) {
    __syncthreads();
#pragma unroll
    for (int c = 0; c < 4; ++c) {
      int ch = wave * 4 + c;                   // 0..15
      int row = ch * 8 + srow8;
      gload_lds16(A + (m0 + row) * K + k0 + sslot * 8, (char*)As + ch * 1024);
      gload_lds16(W + (n0 + row) * K + k0 + sslot * 8, (char*)Bs + ch * 1024);
    }
    __syncthreads();

#pragma unroll
    for (int kk = 0; kk < 2; ++kk) {
      bf16x8 af[4], bfr[4];
#pragma unroll
      for (int i = 0; i < 4; ++i) {
        int row = wr + i * 16 + l15;
        af[i] = *(const bf16x8*)((const char*)As + row * 128 +
                                 ((kk * 64 + g * 16) ^ ((row & 7) << 4)));
      }
#pragma unroll
      for (int i = 0; i < 4; ++i) {
        int row = wc + i * 16 + l15;
        bfr[i] = *(const bf16x8*)((const char*)Bs + row * 128 +
                                  ((kk * 64 + g * 16) ^ ((row & 7) << 4)));
      }
      __builtin_amdgcn_s_setprio(1);
#pragma unroll
      for (int mi = 0; mi < 4; ++mi)
#pragma unroll
        for (int ni = 0; ni < 4; ++ni)
          acc[mi][ni] = MFMA16x16x32(af[mi], bfr[ni], acc[mi][ni]);
      __builtin_amdgcn_s_setprio(0);
    }
  }

#pragma unroll
  for (int ni = 0; ni < 4; ++ni) {
    long col = n0 + wc + ni * 16 + l15;
    float bv = bias[col];
#pragma unroll
    for (int mi = 0; mi < 4; ++mi) {
#pragma unroll
      for (int r = 0; r < 4; ++r) {
        long row = m0 + wr + mi * 16 + g * 4 + r;
        out[row * N + col] = (bf16_t)((acc[mi][ni][r] + bv) * scale);
      }
    }
  }
}

// ---------------- O-projection GEMM: 128x64 tile, f32 out (512 blocks = 2/CU) ----------------
__global__ __launch_bounds__(256, 3) void gemm_o64(
    const bf16_t* __restrict__ A, const bf16_t* __restrict__ W,
    const float* __restrict__ bias, float* __restrict__ out) {
  constexpr int K = 1024, N = 1024;
  __shared__ bf16_t As[128 * 32];
  __shared__ bf16_t Bs[64 * 32];

  const int tid = threadIdx.x;
  const int wave = tid >> 6, lane = tid & 63;
  const int g = lane >> 4, l15 = lane & 15;
  const long m0 = (long)blockIdx.x * 128;
  const long n0 = (long)blockIdx.y * 64;

  const int srow = lane >> 2;
  const int scol = (lane & 3) * 8;

  const int wr = (wave >> 1) * 64;
  const int wc = (wave & 1) * 32;

  f32x4 acc[4][2] = {};

  for (int k0 = 0; k0 < K; k0 += 32) {
    __syncthreads();
#pragma unroll
    for (int c = 0; c < 3; ++c) {
      int idx = wave * 3 + c;            // 0..11 (wave-uniform)
      if (idx < 8) {
        int row = idx * 16 + srow;
        gload_lds16(A + (m0 + row) * K + k0 + scol, (char*)As + idx * 1024);
      } else {
        int row = (idx - 8) * 16 + srow;
        gload_lds16(W + (n0 + row) * K + k0 + scol, (char*)Bs + (idx - 8) * 1024);
      }
    }
    __syncthreads();

    bf16x8 af[4], bfr[2];
#pragma unroll
    for (int i = 0; i < 4; ++i)
      af[i] = *(const bf16x8*)(As + (wr + i * 16 + l15) * 32 + g * 8);
#pragma unroll
    for (int i = 0; i < 2; ++i)
      bfr[i] = *(const bf16x8*)(Bs + (wc + i * 16 + l15) * 32 + g * 8);
    __builtin_amdgcn_s_setprio(1);
#pragma unroll
    for (int mi = 0; mi < 4; ++mi)
#pragma unroll
      for (int ni = 0; ni < 2; ++ni)
        acc[mi][ni] = MFMA16x16x32(af[mi], bfr[ni], acc[mi][ni]);
    __builtin_amdgcn_s_setprio(0);
  }

#pragma unroll
  for (int ni = 0; ni < 2; ++ni) {
    long col = n0 + wc + ni * 16 + l15;
    float bv = bias[col];
#pragma unroll
    for (int mi = 0; mi < 4; ++mi) {
#pragma unroll
      for (int r = 0; r < 4; ++r) {
        long row = m0 + wr + mi * 16 + g * 4 + r;
        out[row * N + col] = acc[mi][ni][r] + bv;
      }
    }
  }
}

// ---------------- Flash attention: QBLK=256, 8 waves (R15, best measured 64.8 us) --------
// grid (8 qb x 32 bh) = 256 blocks x 512 threads (8 waves x 32 q) = 2048 waves = 2/SIMD.
// Per wave per tile: 1 K gload_lds, 2 int2 V loads, 4 int packed LDS writes (8-way
// amortized staging). Log2-domain softmax. Deferred-PV (T15). Mask in LDS (R4 lesson).
// launch_bounds(512,2) -> 1 block/CU, VGPR 88, no spill (R9/R12/R18 rule).
__global__ __launch_bounds__(512, 2) void attn_fwd11(
    const bf16_t* __restrict__ Qm, const bf16_t* __restrict__ Km,
    const bf16_t* __restrict__ Vm, const float* __restrict__ mask,
    bf16_t* __restrict__ ctx) {
  constexpr int S = 2048, Hs = 1024;
  constexpr float L2E = 1.4426950408889634f;
  // bijective XCD swizzle: 256 blocks -> 32 consecutive per XCD (4 bh x 8 qb each)
  int id = blockIdx.y * 8 + blockIdx.x;
  int swz = ((id & 7) << 5) | (id >> 3);
  const int qb = swz & 7;
  const int bh = swz >> 3;
  const int b = bh >> 4, h = bh & 15;

  const int tid = threadIdx.x;          // 0..511
  const int wave = tid >> 6, lane = tid & 63;
  const int l31 = lane & 31, hi = lane >> 5;

  __shared__ bf16_t Kb_[2][64 * 64];   // [key][d], 16B-slot XOR swizzled by (key&7)
  __shared__ bf16_t Vb_[2][64 * 64];   // [d][key], 16B-slot XOR swizzled by (d&7)
  __shared__ float Ms[2048];           // mask row (f32)

  const char* Kg = (const char*)(Km + ((long)b * S) * Hs + h * 64);
  const bf16_t* Vg = Vm + ((long)b * S) * Hs + h * 64;
  const float* mrow = mask + b * S;

  // hoisted Q B-fragments: col=q=l31, k-slot d = ks*16 + hi*8 + j
  const long qrow = (long)b * S + qb * 256 + wave * 32 + l31;
  const bf16_t* Qr = Qm + qrow * Hs + h * 64 + hi * 8;
  bf16x8 qB[4];
#pragma unroll
  for (int ks = 0; ks < 4; ++ks) qB[ks] = *(const bf16x8*)(Qr + ks * 16);

  // V staging: thread covers keys {2ka2, 2ka2+1} x d dq*4..dq*4+3 (512 threads)
  const int ka2 = tid & 31, dq = tid >> 5;   // dq 0..15
  const bf16_t* Vsrc0 = Vg + (long)(2 * ka2) * Hs + dq * 4;

  // K staging: 8 chunks of 1024B (8 rows), 1 per wave; pre-swizzled global source
  const int krow_in8 = lane >> 3;
  const int kslot = (lane & 7) ^ krow_in8;

  // ---- prologue: mask (1 chunk/wave) + tile 0 ----
  gload_lds16((const char*)mrow + wave * 1024 + lane * 16, (char*)Ms + wave * 1024);
  gload_lds16(Kg + (long)(wave * 8 + krow_in8) * (Hs * 2) + kslot * 16,
              (char*)Kb_[0] + wave * 1024);
  int2 v0 = *(const int2*)(Vsrc0);
  int2 v1 = *(const int2*)(Vsrc0 + Hs);
  {
    const u16* p0 = (const u16*)&v0; const u16* p1 = (const u16*)&v1;
#pragma unroll
    for (int j = 0; j < 4; ++j) {
      int d = dq * 4 + j;
      int w = (int)((unsigned)p0[j] | ((unsigned)p1[j] << 16));
      *(int*)((char*)Vb_[0] + d * 128 + ((4 * ka2) ^ ((d & 7) << 4))) = w;
    }
  }
  __syncthreads();

  f32x16 acc0 = {}, acc1 = {};
  float rho = 0.0f, lrun = 0.0f;
  bf16x8 pbP[4] = {};   // packed P(t-1): [st*2+ks2]
  bf16x8 vaP[8] = {};   // V^T frags of tile t-1: [(st*2+ks2)*2+dh]

  for (int t = 0; t < 32; ++t) {
    const int cur = t & 1;
    const char* kb_c = (const char*)Kb_[cur];
    const char* vb_c = (const char*)Vb_[cur];

    // K-fragments for QK (LDS)
    bf16x8 kf0[4], kf1[4];
#pragma unroll
    for (int ks = 0; ks < 4; ++ks)
      kf0[ks] = *(const bf16x8*)(kb_c + l31 * 128 + (((2 * ks + hi) * 16) ^ ((l31 & 7) << 4)));
#pragma unroll
    for (int ks = 0; ks < 4; ++ks) {
      int row = 32 + l31;
      kf1[ks] = *(const bf16x8*)(kb_c + row * 128 + (((2 * ks + hi) * 16) ^ ((row & 7) << 4)));
    }

    // issue next-tile loads early (V reg-loads first, K gload_lds after)
    if (t < 31) {
      const bf16_t* Vs = Vsrc0 + (long)((t + 1) * 64) * Hs;
      v0 = *(const int2*)(Vs);
      v1 = *(const int2*)(Vs + Hs);
      gload_lds16(Kg + (long)((t + 1) * 64 + wave * 8 + krow_in8) * (Hs * 2) + kslot * 16,
                  (char*)Kb_[cur ^ 1] + wave * 1024);
    }
    // mask from LDS (lgkm; broadcast within 32-lane halves)
    const float* mbase = Ms + t * 64;
    float4 mk[8];
#pragma unroll
    for (int st = 0; st < 2; ++st)
#pragma unroll
      for (int rg = 0; rg < 4; ++rg)
        mk[st * 4 + rg] = *(const float4*)(mbase + st * 32 + rg * 8 + hi * 4);

    // ---- QK^T: D[key][q] (log2-domain) ----
    f32x16 sc0 = {}, sc1 = {};
    __builtin_amdgcn_s_setprio(1);
#pragma unroll
    for (int ks = 0; ks < 4; ++ks) sc0 = MFMA32x32x16(kf0[ks], qB[ks], sc0);
#pragma unroll
    for (int ks = 0; ks < 4; ++ks) sc1 = MFMA32x32x16(kf1[ks], qB[ks], sc1);
    __builtin_amdgcn_s_setprio(0);

    // ---- PV(t-1): register-only, independent of tile t -> overlaps softmax below ----
    if (t > 0) {
      __builtin_amdgcn_s_setprio(1);
#pragma unroll
      for (int st = 0; st < 2; ++st)
#pragma unroll
        for (int ks2 = 0; ks2 < 2; ++ks2) {
          int i = st * 2 + ks2;
          acc0 = MFMA32x32x16(vaP[i * 2 + 0], pbP[i], acc0);
          acc1 = MFMA32x32x16(vaP[i * 2 + 1], pbP[i], acc1);
        }
      __builtin_amdgcn_s_setprio(0);
    }

    // ---- read V^T frags of tile t (consumed next iteration; latency-tolerant) ----
#pragma unroll
    for (int st = 0; st < 2; ++st)
#pragma unroll
      for (int ks2 = 0; ks2 < 2; ++ks2) {
        int slot = st * 4 + ks2 * 2 + hi;
        int i = st * 2 + ks2;
        vaP[i * 2 + 0] = *(const bf16x8*)(vb_c + l31 * 128 + ((slot * 16) ^ ((l31 & 7) << 4)));
        int d1 = 32 + l31;
        vaP[i * 2 + 1] = *(const bf16x8*)(vb_c + d1 * 128 + ((slot * 16) ^ ((d1 & 7) << 4)));
      }

    // ---- t = r + mask*log2e; row max via 4 chains ----
    float m4[4] = {-1e30f, -1e30f, -1e30f, -1e30f};
#pragma unroll
    for (int st = 0; st < 2; ++st) {
      f32x16& s = st ? sc1 : sc0;
#pragma unroll
      for (int rg = 0; rg < 4; ++rg) {
        float4 m = mk[st * 4 + rg];
#pragma unroll
        for (int i = 0; i < 4; ++i) {
          float v = fmaf(((const float*)&m)[i], L2E, s[rg * 4 + i]);
          s[rg * 4 + i] = v;
          m4[i] = fmaxf(m4[i], v);
        }
      }
    }
    float mt = fmaxf(fmaxf(m4[0], m4[1]), fmaxf(m4[2], m4[3]));
    mt = fmaxf(mt, __shfl_xor(mt, 32, 64));

    // ---- rare rescale: keep exp2 arg <= 24 (acc already holds PV(t-1): consistent) ----
    if (!__all(mt - rho <= 24.0f)) {
      float mw = mt;
#pragma unroll
      for (int off = 1; off < 32; off <<= 1) mw = fmaxf(mw, __shfl_xor(mw, off, 64));
      float fct = exp2_fast(rho - mw);   // uniform
      lrun *= fct;
#pragma unroll
      for (int i = 0; i < 16; ++i) { acc0[i] *= fct; acc1[i] *= fct; }
      rho = mw;
    }
    float rho_u = __builtin_amdgcn_readfirstlane(rho);
    if (rho_u != 0.0f) {
#pragma unroll
      for (int i = 0; i < 16; ++i) { sc0[i] -= rho_u; sc1[i] -= rho_u; }
    }

    // ---- p = exp2(t); sum via 4 chains ----
    float s4[4] = {0.f, 0.f, 0.f, 0.f};
#pragma unroll
    for (int st = 0; st < 2; ++st) {
      f32x16& s = st ? sc1 : sc0;
#pragma unroll
      for (int i = 0; i < 16; ++i) {
        float p = exp2_fast(s[i]);
        s[i] = p;
        s4[i & 3] += p;
      }
    }
    float ls = (s4[0] + s4[1]) + (s4[2] + s4[3]);
    ls += __shfl_xor(ls, 32, 64);
    lrun += ls;

    // ---- pack P(t) -> pbP (consumed next iteration) ----
#pragma unroll
    for (int st = 0; st < 2; ++st) {
      f32x16& s = st ? sc1 : sc0;
      unsigned a0 = pk2(s[0], s[1]),   b0 = pk2(s[4], s[5]);
      unsigned a1 = pk2(s[2], s[3]),   b1 = pk2(s[6], s[7]);
      unsigned a2 = pk2(s[8], s[9]),   b2 = pk2(s[12], s[13]);
      unsigned a3 = pk2(s[10], s[11]), b3 = pk2(s[14], s[15]);
      asm("v_permlane32_swap_b32 %0, %1" : "+v"(a0), "+v"(b0));
      asm("v_permlane32_swap_b32 %0, %1" : "+v"(a1), "+v"(b1));
      asm("v_permlane32_swap_b32 %0, %1" : "+v"(a2), "+v"(b2));
      asm("v_permlane32_swap_b32 %0, %1" : "+v"(a3), "+v"(b3));
      pbP[st * 2 + 0] = mk_frag(a0, a1, b0, b1);   // keys st*32 + 0..15
      pbP[st * 2 + 1] = mk_frag(a2, a3, b2, b3);   // keys st*32 + 16..31
    }

    // ---- write next V tile ----
    if (t < 31) {
      const u16* p0 = (const u16*)&v0; const u16* p1 = (const u16*)&v1;
      char* vb_n = (char*)Vb_[cur ^ 1];
#pragma unroll
      for (int j = 0; j < 4; ++j) {
        int d = dq * 4 + j;
        int w = (int)((unsigned)p0[j] | ((unsigned)p1[j] << 16));
        *(int*)(vb_n + d * 128 + ((4 * ka2) ^ ((d & 7) << 4))) = w;
      }
    }
    __syncthreads();
  }

  // ---- epilogue: flush PV(31) ----
  __builtin_amdgcn_s_setprio(1);
#pragma unroll
  for (int st = 0; st < 2; ++st)
#pragma unroll
    for (int ks2 = 0; ks2 < 2; ++ks2) {
      int i = st * 2 + ks2;
      acc0 = MFMA32x32x16(vaP[i * 2 + 0], pbP[i], acc0);
      acc1 = MFMA32x32x16(vaP[i * 2 + 1], pbP[i], acc1);
    }
  __builtin_amdgcn_s_setprio(0);

  // ---- D2 col=q=l31, row d = dh*32 + (r&3)+8*(r>>2)+4*hi ----
  float inv = 1.0f / lrun;
  bf16_t* cb = ctx + qrow * Hs + h * 64;
#pragma unroll
  for (int dh = 0; dh < 2; ++dh) {
    f32x16& a = dh ? acc1 : acc0;
#pragma unroll
    for (int rg = 0; rg < 4; ++rg) {
      ushort4 o;
      o.x = bits_of((bf16_t)(a[rg * 4 + 0] * inv));
      o.y = bits_of((bf16_t)(a[rg * 4 + 1] * inv));
      o.z = bits_of((bf16_t)(a[rg * 4 + 2] * inv));
      o.w = bits_of((bf16_t)(a[rg * 4 + 3] * inv));
      *(ushort4*)(cb + dh * 32 + rg * 8 + hi * 4) = o;
    }
  }
}

// ---------------- launcher ----------------
extern "C" void kernel_launch(void* const* d_in, const int* in_sizes, int n_in,
                              void* d_out, int out_size, void* d_ws, size_t ws_size,
                              hipStream_t stream) {
  (void)in_sizes; (void)n_in; (void)out_size; (void)ws_size;
  const float* X  = (const float*)d_in[0];
  const float* mask = (const float*)d_in[1];
  const float* Wq = (const float*)d_in[2];
  const float* bq = (const float*)d_in[3];
  const float* Wk = (const float*)d_in[4];
  const float* bk = (const float*)d_in[5];
  const float* Wv = (const float*)d_in[6];
  const float* bv = (const float*)d_in[7];
  const float* Wo = (const float*)d_in[8];
  const float* bo = (const float*)d_in[9];

  char* ws = (char*)d_ws;
  bf16_t* Xb  = (bf16_t*)(ws + 0);          // dead after QKV GEMM
  bf16_t* Wqb = (bf16_t*)(ws + 8388608);
  bf16_t* Wkb = (bf16_t*)(ws + 10485760);
  bf16_t* Wvb = (bf16_t*)(ws + 12582912);
  bf16_t* Wob = (bf16_t*)(ws + 14680064);   // LIVE until O-GEMM
  bf16_t* Qb  = (bf16_t*)(ws + 16777216);
  bf16_t* Kb  = (bf16_t*)(ws + 25165824);
  bf16_t* Vb  = (bf16_t*)(ws + 33554432);
  bf16_t* Cb  = (bf16_t*)(ws + 41943040);   // ctx bf16 (dedicated)

  cvt_all<<<8192, 256, 0, stream>>>((const float4*)X, (const float4*)Wq, (const float4*)Wk,
                                    (const float4*)Wv, (const float4*)Wo, (ushort4*)Xb);

  // QKV projections; Q pre-scaled by 0.125*log2e so attention scores are log2-domain
  const float QSCALE = 0.125f * 1.4426950408889634f;
  dim3 gq(32, 8, 3);
  gemm_bt<<<gq, 256, 0, stream>>>(Xb, Wqb, Wkb, Wvb, bq, bk, bv, Qb, Kb, Vb,
                                  QSCALE, 1.0f, 1.0f);

  // attention (QBLK=256, 8-wave staging amortization -- R15 best)
  dim3 ga(8, 32, 1);
  attn_fwd11<<<ga, 512, 0, stream>>>(Qb, Kb, Vb, mask, Cb);

  // output projection -> f32 d_out (128x64 tiles, 512 blocks = 2/CU)
  dim3 go(32, 16, 1);
  gemm_o64<<<go, 256, 0, stream>>>(Cb, Wob, bo, (float*)d_out);
}

// Round 21
// 122.081 us; speedup vs baseline: 1.0153x; 1.0153x over previous
//
#include <hip/hip_runtime.h>
#include <hip/hip_bf16.h>

typedef __bf16 bf16_t;
typedef __bf16 bf16x8 __attribute__((ext_vector_type(8)));
typedef float f32x4 __attribute__((ext_vector_type(4)));
typedef float f32x16 __attribute__((ext_vector_type(16)));
typedef unsigned short u16;

#define DEVI __device__ __forceinline__
#define MFMA16x16x32(A, B, C) __builtin_amdgcn_mfma_f32_16x16x32_bf16(A, B, C, 0, 0, 0)
#define MFMA32x32x16(A, B, C) __builtin_amdgcn_mfma_f32_32x32x16_bf16(A, B, C, 0, 0, 0)

DEVI void gload_lds16(const void* g, void* l) {
  __builtin_amdgcn_global_load_lds(
      (const __attribute__((address_space(1))) void*)g,
      (__attribute__((address_space(3))) void*)l, 16, 0, 0);
}

DEVI u16 bits_of(bf16_t x) { return __builtin_bit_cast(u16, x); }

DEVI unsigned pk2(float lo, float hi) {
  return (unsigned)bits_of((bf16_t)lo) | ((unsigned)bits_of((bf16_t)hi) << 16);
}

DEVI bf16x8 mk_frag(unsigned s0, unsigned s1, unsigned s2, unsigned s3) {
  int4 t;
  t.x = (int)s0; t.y = (int)s1; t.z = (int)s2; t.w = (int)s3;
  return __builtin_bit_cast(bf16x8, t);
}

#if __has_builtin(__builtin_amdgcn_exp2f)
DEVI float exp2_fast(float x) { return __builtin_amdgcn_exp2f(x); }
#else
DEVI float exp2_fast(float x) { return __exp2f(x); }
#endif

// ---------------- fused fp32 -> bf16 conversion: X + 4 weight matrices ----------------
__global__ void cvt_all(const float4* __restrict__ X,
                        const float4* __restrict__ Wq, const float4* __restrict__ Wk,
                        const float4* __restrict__ Wv, const float4* __restrict__ Wo,
                        ushort4* __restrict__ out) {
  int i = blockIdx.x * 256 + threadIdx.x;   // 0 .. 2097151 float4s
  const float4* src;
  int off;
  if (i < 1048576) { src = X; off = i; }
  else {
    int j = i - 1048576;
    int seg = j >> 18;
    off = j & 262143;
    src = (seg == 0) ? Wq : (seg == 1) ? Wk : (seg == 2) ? Wv : Wo;
  }
  float4 v = src[off];
  ushort4 o;
  o.x = bits_of((bf16_t)v.x);
  o.y = bits_of((bf16_t)v.y);
  o.z = bits_of((bf16_t)v.z);
  o.w = bits_of((bf16_t)v.w);
  out[i] = o;
}

// ---------------- QKV GEMM: 128x128 tile, BK=32, bf16 out (proven ~760 TF) ----------------
// R20 lesson: BK=64 doesn't help -- the pre-barrier vmcnt(0) drain is load-latency-bound,
// not barrier-count-bound; halving barriers doubles the drained latency per barrier.
__global__ __launch_bounds__(256, 3) void gemm_bt(
    const bf16_t* __restrict__ A,
    const bf16_t* __restrict__ W0, const bf16_t* __restrict__ W1, const bf16_t* __restrict__ W2,
    const float* __restrict__ b0, const float* __restrict__ b1, const float* __restrict__ b2,
    bf16_t* o0, bf16_t* o1, bf16_t* o2, float s0, float s1, float s2) {
  constexpr int K = 1024, N = 1024;
  const int z = blockIdx.z;
  const bf16_t* W = (z == 0) ? W0 : ((z == 1) ? W1 : W2);
  const float* bias = (z == 0) ? b0 : ((z == 1) ? b1 : b2);
  bf16_t* out = (z == 0) ? o0 : ((z == 1) ? o1 : o2);
  const float scale = (z == 0) ? s0 : ((z == 1) ? s1 : s2);

  __shared__ bf16_t As[128 * 32];
  __shared__ bf16_t Bs[128 * 32];

  const int tid = threadIdx.x;
  const int wave = tid >> 6, lane = tid & 63;
  const int g = lane >> 4, l15 = lane & 15;
  const long m0 = (long)blockIdx.x * 128;
  const long n0 = (long)blockIdx.y * 128;

  const int srow = lane >> 2;
  const int scol = (lane & 3) * 8;

  const int wr = (wave >> 1) * 64;
  const int wc = (wave & 1) * 64;

  f32x4 acc[4][4] = {};

  for (int k0 = 0; k0 < K; k0 += 32) {
    __syncthreads();
#pragma unroll
    for (int t = 0; t < 2; ++t) {
      int chunk = wave * 2 + t;
      int row = chunk * 16 + srow;
      gload_lds16(A + (m0 + row) * K + k0 + scol, (char*)As + chunk * 1024);
      gload_lds16(W + (n0 + row) * K + k0 + scol, (char*)Bs + chunk * 1024);
    }
    __syncthreads();

    bf16x8 af[4], bfr[4];
#pragma unroll
    for (int i = 0; i < 4; ++i)
      af[i] = *(const bf16x8*)(As + (wr + i * 16 + l15) * 32 + g * 8);
#pragma unroll
    for (int i = 0; i < 4; ++i)
      bfr[i] = *(const bf16x8*)(Bs + (wc + i * 16 + l15) * 32 + g * 8);
    __builtin_amdgcn_s_setprio(1);
#pragma unroll
    for (int mi = 0; mi < 4; ++mi)
#pragma unroll
      for (int ni = 0; ni < 4; ++ni)
        acc[mi][ni] = MFMA16x16x32(af[mi], bfr[ni], acc[mi][ni]);
    __builtin_amdgcn_s_setprio(0);
  }

#pragma unroll
  for (int ni = 0; ni < 4; ++ni) {
    long col = n0 + wc + ni * 16 + l15;
    float bv = bias[col];
#pragma unroll
    for (int mi = 0; mi < 4; ++mi) {
#pragma unroll
      for (int r = 0; r < 4; ++r) {
        long row = m0 + wr + mi * 16 + g * 4 + r;
        out[row * N + col] = (bf16_t)((acc[mi][ni][r] + bv) * scale);
      }
    }
  }
}

// ---------------- O-projection GEMM: 128x64 tile, f32 out (512 blocks = 2/CU) ----------------
__global__ __launch_bounds__(256, 3) void gemm_o64(
    const bf16_t* __restrict__ A, const bf16_t* __restrict__ W,
    const float* __restrict__ bias, float* __restrict__ out) {
  constexpr int K = 1024, N = 1024;
  __shared__ bf16_t As[128 * 32];
  __shared__ bf16_t Bs[64 * 32];

  const int tid = threadIdx.x;
  const int wave = tid >> 6, lane = tid & 63;
  const int g = lane >> 4, l15 = lane & 15;
  const long m0 = (long)blockIdx.x * 128;
  const long n0 = (long)blockIdx.y * 64;

  const int srow = lane >> 2;
  const int scol = (lane & 3) * 8;

  const int wr = (wave >> 1) * 64;
  const int wc = (wave & 1) * 32;

  f32x4 acc[4][2] = {};

  for (int k0 = 0; k0 < K; k0 += 32) {
    __syncthreads();
#pragma unroll
    for (int c = 0; c < 3; ++c) {
      int idx = wave * 3 + c;            // 0..11 (wave-uniform)
      if (idx < 8) {
        int row = idx * 16 + srow;
        gload_lds16(A + (m0 + row) * K + k0 + scol, (char*)As + idx * 1024);
      } else {
        int row = (idx - 8) * 16 + srow;
        gload_lds16(W + (n0 + row) * K + k0 + scol, (char*)Bs + (idx - 8) * 1024);
      }
    }
    __syncthreads();

    bf16x8 af[4], bfr[2];
#pragma unroll
    for (int i = 0; i < 4; ++i)
      af[i] = *(const bf16x8*)(As + (wr + i * 16 + l15) * 32 + g * 8);
#pragma unroll
    for (int i = 0; i < 2; ++i)
      bfr[i] = *(const bf16x8*)(Bs + (wc + i * 16 + l15) * 32 + g * 8);
    __builtin_amdgcn_s_setprio(1);
#pragma unroll
    for (int mi = 0; mi < 4; ++mi)
#pragma unroll
      for (int ni = 0; ni < 2; ++ni)
        acc[mi][ni] = MFMA16x16x32(af[mi], bfr[ni], acc[mi][ni]);
    __builtin_amdgcn_s_setprio(0);
  }

#pragma unroll
  for (int ni = 0; ni < 2; ++ni) {
    long col = n0 + wc + ni * 16 + l15;
    float bv = bias[col];
#pragma unroll
    for (int mi = 0; mi < 4; ++mi) {
#pragma unroll
      for (int r = 0; r < 4; ++r) {
        long row = m0 + wr + mi * 16 + g * 4 + r;
        out[row * N + col] = acc[mi][ni][r] + bv;
      }
    }
  }
}

// ---------------- Flash attention: QBLK=256, 8 waves (R15, best measured 64.8 us) --------
// grid (8 qb x 32 bh) = 256 blocks x 512 threads (8 waves x 32 q) = 2048 waves = 2/SIMD.
// Per wave per tile: 1 K gload_lds, 2 int2 V loads, 4 int packed LDS writes (8-way
// amortized staging). Log2-domain softmax (Q pre-scaled 0.125*log2e; mask via fma in LDS;
// exp2 direct; uniform deferred rho). Deferred-PV (T15): PV(t-1) register-only overlaps
// softmax(t). Mask in LDS (lgkm only -- R4 lesson). launch_bounds(512,2) -> 1 block/CU,
// VGPR 88, no spill (R9/R12/R18 rule: persistent state beyond ~100 VGPRs spills).
// R16: latency-bound below ~46% VALUBusy. R18: KVBLK=64 is the register-feasible max.
__global__ __launch_bounds__(512, 2) void attn_fwd11(
    const bf16_t* __restrict__ Qm, const bf16_t* __restrict__ Km,
    const bf16_t* __restrict__ Vm, const float* __restrict__ mask,
    bf16_t* __restrict__ ctx) {
  constexpr int S = 2048, Hs = 1024;
  constexpr float L2E = 1.4426950408889634f;
  // bijective XCD swizzle: 256 blocks -> 32 consecutive per XCD (4 bh x 8 qb each)
  int id = blockIdx.y * 8 + blockIdx.x;
  int swz = ((id & 7) << 5) | (id >> 3);
  const int qb = swz & 7;
  const int bh = swz >> 3;
  const int b = bh >> 4, h = bh & 15;

  const int tid = threadIdx.x;          // 0..511
  const int wave = tid >> 6, lane = tid & 63;
  const int l31 = lane & 31, hi = lane >> 5;

  __shared__ bf16_t Kb_[2][64 * 64];   // [key][d], 16B-slot XOR swizzled by (key&7)
  __shared__ bf16_t Vb_[2][64 * 64];   // [d][key], 16B-slot XOR swizzled by (d&7)
  __shared__ float Ms[2048];           // mask row (f32)

  const char* Kg = (const char*)(Km + ((long)b * S) * Hs + h * 64);
  const bf16_t* Vg = Vm + ((long)b * S) * Hs + h * 64;
  const float* mrow = mask + b * S;

  // hoisted Q B-fragments: col=q=l31, k-slot d = ks*16 + hi*8 + j
  const long qrow = (long)b * S + qb * 256 + wave * 32 + l31;
  const bf16_t* Qr = Qm + qrow * Hs + h * 64 + hi * 8;
  bf16x8 qB[4];
#pragma unroll
  for (int ks = 0; ks < 4; ++ks) qB[ks] = *(const bf16x8*)(Qr + ks * 16);

  // V staging: thread covers keys {2ka2, 2ka2+1} x d dq*4..dq*4+3 (512 threads)
  const int ka2 = tid & 31, dq = tid >> 5;   // dq 0..15
  const bf16_t* Vsrc0 = Vg + (long)(2 * ka2) * Hs + dq * 4;

  // K staging: 8 chunks of 1024B (8 rows), 1 per wave; pre-swizzled global source
  const int krow_in8 = lane >> 3;
  const int kslot = (lane & 7) ^ krow_in8;

  // ---- prologue: mask (1 chunk/wave) + tile 0 ----
  gload_lds16((const char*)mrow + wave * 1024 + lane * 16, (char*)Ms + wave * 1024);
  gload_lds16(Kg + (long)(wave * 8 + krow_in8) * (Hs * 2) + kslot * 16,
              (char*)Kb_[0] + wave * 1024);
  int2 v0 = *(const int2*)(Vsrc0);
  int2 v1 = *(const int2*)(Vsrc0 + Hs);
  {
    const u16* p0 = (const u16*)&v0; const u16* p1 = (const u16*)&v1;
#pragma unroll
    for (int j = 0; j < 4; ++j) {
      int d = dq * 4 + j;
      int w = (int)((unsigned)p0[j] | ((unsigned)p1[j] << 16));
      *(int*)((char*)Vb_[0] + d * 128 + ((4 * ka2) ^ ((d & 7) << 4))) = w;
    }
  }
  __syncthreads();

  f32x16 acc0 = {}, acc1 = {};
  float rho = 0.0f, lrun = 0.0f;
  bf16x8 pbP[4] = {};   // packed P(t-1): [st*2+ks2]
  bf16x8 vaP[8] = {};   // V^T frags of tile t-1: [(st*2+ks2)*2+dh]

  for (int t = 0; t < 32; ++t) {
    const int cur = t & 1;
    const char* kb_c = (const char*)Kb_[cur];
    const char* vb_c = (const char*)Vb_[cur];

    // K-fragments for QK (LDS)
    bf16x8 kf0[4], kf1[4];
#pragma unroll
    for (int ks = 0; ks < 4; ++ks)
      kf0[ks] = *(const bf16x8*)(kb_c + l31 * 128 + (((2 * ks + hi) * 16) ^ ((l31 & 7) << 4)));
#pragma unroll
    for (int ks = 0; ks < 4; ++ks) {
      int row = 32 + l31;
      kf1[ks] = *(const bf16x8*)(kb_c + row * 128 + (((2 * ks + hi) * 16) ^ ((row & 7) << 4)));
    }

    // issue next-tile loads early (V reg-loads first, K gload_lds after)
    if (t < 31) {
      const bf16_t* Vs = Vsrc0 + (long)((t + 1) * 64) * Hs;
      v0 = *(const int2*)(Vs);
      v1 = *(const int2*)(Vs + Hs);
      gload_lds16(Kg + (long)((t + 1) * 64 + wave * 8 + krow_in8) * (Hs * 2) + kslot * 16,
                  (char*)Kb_[cur ^ 1] + wave * 1024);
    }
    // mask from LDS (lgkm; broadcast within 32-lane halves)
    const float* mbase = Ms + t * 64;
    float4 mk[8];
#pragma unroll
    for (int st = 0; st < 2; ++st)
#pragma unroll
      for (int rg = 0; rg < 4; ++rg)
        mk[st * 4 + rg] = *(const float4*)(mbase + st * 32 + rg * 8 + hi * 4);

    // ---- QK^T: D[key][q] (log2-domain) ----
    f32x16 sc0 = {}, sc1 = {};
    __builtin_amdgcn_s_setprio(1);
#pragma unroll
    for (int ks = 0; ks < 4; ++ks) sc0 = MFMA32x32x16(kf0[ks], qB[ks], sc0);
#pragma unroll
    for (int ks = 0; ks < 4; ++ks) sc1 = MFMA32x32x16(kf1[ks], qB[ks], sc1);
    __builtin_amdgcn_s_setprio(0);

    // ---- PV(t-1): register-only, independent of tile t -> overlaps softmax below ----
    if (t > 0) {
      __builtin_amdgcn_s_setprio(1);
#pragma unroll
      for (int st = 0; st < 2; ++st)
#pragma unroll
        for (int ks2 = 0; ks2 < 2; ++ks2) {
          int i = st * 2 + ks2;
          acc0 = MFMA32x32x16(vaP[i * 2 + 0], pbP[i], acc0);
          acc1 = MFMA32x32x16(vaP[i * 2 + 1], pbP[i], acc1);
        }
      __builtin_amdgcn_s_setprio(0);
    }

    // ---- read V^T frags of tile t (consumed next iteration; latency-tolerant) ----
#pragma unroll
    for (int st = 0; st < 2; ++st)
#pragma unroll
      for (int ks2 = 0; ks2 < 2; ++ks2) {
        int slot = st * 4 + ks2 * 2 + hi;
        int i = st * 2 + ks2;
        vaP[i * 2 + 0] = *(const bf16x8*)(vb_c + l31 * 128 + ((slot * 16) ^ ((l31 & 7) << 4)));
        int d1 = 32 + l31;
        vaP[i * 2 + 1] = *(const bf16x8*)(vb_c + d1 * 128 + ((slot * 16) ^ ((d1 & 7) << 4)));
      }

    // ---- t = r + mask*log2e; row max via 4 chains ----
    float m4[4] = {-1e30f, -1e30f, -1e30f, -1e30f};
#pragma unroll
    for (int st = 0; st < 2; ++st) {
      f32x16& s = st ? sc1 : sc0;
#pragma unroll
      for (int rg = 0; rg < 4; ++rg) {
        float4 m = mk[st * 4 + rg];
#pragma unroll
        for (int i = 0; i < 4; ++i) {
          float v = fmaf(((const float*)&m)[i], L2E, s[rg * 4 + i]);
          s[rg * 4 + i] = v;
          m4[i] = fmaxf(m4[i], v);
        }
      }
    }
    float mt = fmaxf(fmaxf(m4[0], m4[1]), fmaxf(m4[2], m4[3]));
    mt = fmaxf(mt, __shfl_xor(mt, 32, 64));

    // ---- rare rescale: keep exp2 arg <= 24 (acc already holds PV(t-1): consistent) ----
    if (!__all(mt - rho <= 24.0f)) {
      float mw = mt;
#pragma unroll
      for (int off = 1; off < 32; off <<= 1) mw = fmaxf(mw, __shfl_xor(mw, off, 64));
      float fct = exp2_fast(rho - mw);   // uniform
      lrun *= fct;
#pragma unroll
      for (int i = 0; i < 16; ++i) { acc0[i] *= fct; acc1[i] *= fct; }
      rho = mw;
    }
    float rho_u = __builtin_amdgcn_readfirstlane(rho);
    if (rho_u != 0.0f) {
#pragma unroll
      for (int i = 0; i < 16; ++i) { sc0[i] -= rho_u; sc1[i] -= rho_u; }
    }

    // ---- p = exp2(t); sum via 4 chains ----
    float s4[4] = {0.f, 0.f, 0.f, 0.f};
#pragma unroll
    for (int st = 0; st < 2; ++st) {
      f32x16& s = st ? sc1 : sc0;
#pragma unroll
      for (int i = 0; i < 16; ++i) {
        float p = exp2_fast(s[i]);
        s[i] = p;
        s4[i & 3] += p;
      }
    }
    float ls = (s4[0] + s4[1]) + (s4[2] + s4[3]);
    ls += __shfl_xor(ls, 32, 64);
    lrun += ls;

    // ---- pack P(t) -> pbP (consumed next iteration) ----
#pragma unroll
    for (int st = 0; st < 2; ++st) {
      f32x16& s = st ? sc1 : sc0;
      unsigned a0 = pk2(s[0], s[1]),   b0 = pk2(s[4], s[5]);
      unsigned a1 = pk2(s[2], s[3]),   b1 = pk2(s[6], s[7]);
      unsigned a2 = pk2(s[8], s[9]),   b2 = pk2(s[12], s[13]);
      unsigned a3 = pk2(s[10], s[11]), b3 = pk2(s[14], s[15]);
      asm("v_permlane32_swap_b32 %0, %1" : "+v"(a0), "+v"(b0));
      asm("v_permlane32_swap_b32 %0, %1" : "+v"(a1), "+v"(b1));
      asm("v_permlane32_swap_b32 %0, %1" : "+v"(a2), "+v"(b2));
      asm("v_permlane32_swap_b32 %0, %1" : "+v"(a3), "+v"(b3));
      pbP[st * 2 + 0] = mk_frag(a0, a1, b0, b1);   // keys st*32 + 0..15
      pbP[st * 2 + 1] = mk_frag(a2, a3, b2, b3);   // keys st*32 + 16..31
    }

    // ---- write next V tile ----
    if (t < 31) {
      const u16* p0 = (const u16*)&v0; const u16* p1 = (const u16*)&v1;
      char* vb_n = (char*)Vb_[cur ^ 1];
#pragma unroll
      for (int j = 0; j < 4; ++j) {
        int d = dq * 4 + j;
        int w = (int)((unsigned)p0[j] | ((unsigned)p1[j] << 16));
        *(int*)(vb_n + d * 128 + ((4 * ka2) ^ ((d & 7) << 4))) = w;
      }
    }
    __syncthreads();
  }

  // ---- epilogue: flush PV(31) ----
  __builtin_amdgcn_s_setprio(1);
#pragma unroll
  for (int st = 0; st < 2; ++st)
#pragma unroll
    for (int ks2 = 0; ks2 < 2; ++ks2) {
      int i = st * 2 + ks2;
      acc0 = MFMA32x32x16(vaP[i * 2 + 0], pbP[i], acc0);
      acc1 = MFMA32x32x16(vaP[i * 2 + 1], pbP[i], acc1);
    }
  __builtin_amdgcn_s_setprio(0);

  // ---- D2 col=q=l31, row d = dh*32 + (r&3)+8*(r>>2)+4*hi ----
  float inv = 1.0f / lrun;
  bf16_t* cb = ctx + qrow * Hs + h * 64;
#pragma unroll
  for (int dh = 0; dh < 2; ++dh) {
    f32x16& a = dh ? acc1 : acc0;
#pragma unroll
    for (int rg = 0; rg < 4; ++rg) {
      ushort4 o;
      o.x = bits_of((bf16_t)(a[rg * 4 + 0] * inv));
      o.y = bits_of((bf16_t)(a[rg * 4 + 1] * inv));
      o.z = bits_of((bf16_t)(a[rg * 4 + 2] * inv));
      o.w = bits_of((bf16_t)(a[rg * 4 + 3] * inv));
      *(ushort4*)(cb + dh * 32 + rg * 8 + hi * 4) = o;
    }
  }
}

// ---------------- launcher ----------------
extern "C" void kernel_launch(void* const* d_in, const int* in_sizes, int n_in,
                              void* d_out, int out_size, void* d_ws, size_t ws_size,
                              hipStream_t stream) {
  (void)in_sizes; (void)n_in; (void)out_size; (void)ws_size;
  const float* X  = (const float*)d_in[0];
  const float* mask = (const float*)d_in[1];
  const float* Wq = (const float*)d_in[2];
  const float* bq = (const float*)d_in[3];
  const float* Wk = (const float*)d_in[4];
  const float* bk = (const float*)d_in[5];
  const float* Wv = (const float*)d_in[6];
  const float* bv = (const float*)d_in[7];
  const float* Wo = (const float*)d_in[8];
  const float* bo = (const float*)d_in[9];

  char* ws = (char*)d_ws;
  bf16_t* Xb  = (bf16_t*)(ws + 0);          // dead after QKV GEMM
  bf16_t* Wqb = (bf16_t*)(ws + 8388608);
  bf16_t* Wkb = (bf16_t*)(ws + 10485760);
  bf16_t* Wvb = (bf16_t*)(ws + 12582912);
  bf16_t* Wob = (bf16_t*)(ws + 14680064);   // LIVE until O-GEMM
  bf16_t* Qb  = (bf16_t*)(ws + 16777216);
  bf16_t* Kb  = (bf16_t*)(ws + 25165824);
  bf16_t* Vb  = (bf16_t*)(ws + 33554432);
  bf16_t* Cb  = (bf16_t*)(ws + 41943040);   // ctx bf16 (dedicated)

  cvt_all<<<8192, 256, 0, stream>>>((const float4*)X, (const float4*)Wq, (const float4*)Wk,
                                    (const float4*)Wv, (const float4*)Wo, (ushort4*)Xb);

  // QKV projections; Q pre-scaled by 0.125*log2e so attention scores are log2-domain
  const float QSCALE = 0.125f * 1.4426950408889634f;
  dim3 gq(32, 8, 3);
  gemm_bt<<<gq, 256, 0, stream>>>(Xb, Wqb, Wkb, Wvb, bq, bk, bv, Qb, Kb, Vb,
                                  QSCALE, 1.0f, 1.0f);

  // attention (QBLK=256, 8-wave staging amortization -- R15 best)
  dim3 ga(8, 32, 1);
  attn_fwd11<<<ga, 512, 0, stream>>>(Qb, Kb, Vb, mask, Cb);

  // output projection -> f32 d_out (128x64 tiles, 512 blocks = 2/CU)
  dim3 go(32, 16, 1);
  gemm_o64<<<go, 256, 0, stream>>>(Cb, Wob, bo, (float*)d_out);
}